// Round 7
// baseline (210.292 us; speedup 1.0000x reference)
//
#include <hip/hip_runtime.h>

// FCPlanenet on MI355X (gfx950). fp32 inputs, fp32 output [32*9].
// Round 7: occupancy + VALU diet on the verified round-6 dataflow.
//  - LDS transpose tile now bf16 (post-relu, bias folded): 17.4 KB vs 33.8 KB
//    -> 8 blocks/CU (middle layers). h-store = pure u16x8 copy; pm = integer
//    max (non-negative bf16 sorts as uint).
//  - native __bf16 casts (compiler emits v_cvt_pk_bf16_f32; RNE, identical
//    to previous manual f2bf).
//  - k_layer: h already relu'd by producer -> A-frag load is a straight copy.
// h layout (frag order, verified R6): slot (tile, ks, lane) holds
//   rows tile*16+(lane&15), cols ks*32+(lane>>4)*8+j.
// C/D map (probe-verified R3/R4): col=lane&15, row=(lane>>4)*4+r.

using bf16x8 = __attribute__((ext_vector_type(8))) __bf16;
using u16x8  = __attribute__((ext_vector_type(8))) unsigned short;
using f32x4  = __attribute__((ext_vector_type(4))) float;

__device__ __forceinline__ unsigned short f2bf(float x) {
  __bf16 b = (__bf16)x;                       // RNE via v_cvt_pk_bf16_f32
  return __builtin_bit_cast(unsigned short, b);
}

__device__ __forceinline__ f32x4 mfma16(bf16x8 a, bf16x8 b, f32x4 c) {
  return __builtin_amdgcn_mfma_f32_16x16x32_bf16(a, b, c, 0, 0, 0);
}

union FragU { unsigned short us[8]; u16x8 u; bf16x8 v; };

// ---------------------------------------------------------------------------
// Pack all four W (fp32 KxN, N=128) -> frag-ordered bf16 into one buffer.
// ---------------------------------------------------------------------------
__global__ __launch_bounds__(256) void k_pack_all(
    const float* __restrict__ W0, const float* __restrict__ W1,
    const float* __restrict__ W2, const float* __restrict__ W3,
    unsigned short* __restrict__ Wt) {
  const int blk = blockIdx.x, t = threadIdx.x;
  const float* src; int slot; unsigned short* dst;
  if (blk < 16)      { src = W0; slot = blk * 256 + t;        dst = Wt; }
  else if (blk < 24) { src = W1; slot = (blk - 16) * 256 + t; dst = Wt + 32768; }
  else if (blk < 32) { src = W2; slot = (blk - 24) * 256 + t; dst = Wt + 49152; }
  else               { src = W3; slot = (blk - 32) * 256 + t; dst = Wt + 65536; }
  const int ks = slot >> 9, rem = slot & 511;
  const int nt = rem >> 6, lane = rem & 63;
  const int n = nt * 16 + (lane & 15);
  const int kb = ks * 32 + ((lane >> 4) << 3);
  FragU fr;
#pragma unroll
  for (int j = 0; j < 8; ++j) fr.us[j] = f2bf(src[(kb + j) * 128 + n]);
  reinterpret_cast<u16x8*>(dst)[slot] = fr.u;
}

// ---------------------------------------------------------------------------
// Shared epilogue: acc+bias -> relu -> bf16 LDS tile (stride 136) ->
//   {pm integer-max + shuffle, frag-order h copy}.
// ---------------------------------------------------------------------------
__device__ __forceinline__ void epilogue16(
    unsigned short* hs, unsigned short (*pmaxs)[128], const f32x4 (&acc)[8],
    const float (&bias)[8], int t, int blk, unsigned short* __restrict__ h,
    float* __restrict__ pm, bool write_h) {
  const int w = t >> 6, lane = t & 63, g = lane >> 4, c = lane & 15;
#pragma unroll
  for (int nt = 0; nt < 8; ++nt) {
#pragma unroll
    for (int r = 0; r < 4; ++r) {
      const float v = fmaxf(acc[nt][r] + bias[nt], 0.f);
      hs[(w * 16 + g * 4 + r) * 136 + nt * 16 + c] = f2bf(v);
    }
  }
  __syncthreads();

  // pm: thread -> rows (t>>4)*4..+3, cols (t&15)*8..+7; integer max (bf16>=0)
  {
    const int rg = t >> 4, cb = t & 15;
    int mx[8];
#pragma unroll
    for (int j = 0; j < 8; ++j) mx[j] = 0;
#pragma unroll
    for (int rr = 0; rr < 4; ++rr) {
      const u16x8 vv = *reinterpret_cast<const u16x8*>(&hs[(rg * 4 + rr) * 136 + cb * 8]);
#pragma unroll
      for (int j = 0; j < 8; ++j) mx[j] = max(mx[j], (int)vv[j]);
    }
#pragma unroll
    for (int j = 0; j < 8; ++j) {
      mx[j] = max(mx[j], __shfl_xor(mx[j], 16, 64));
      mx[j] = max(mx[j], __shfl_xor(mx[j], 32, 64));
    }
    if (lane < 16) {
#pragma unroll
      for (int j = 0; j < 8; ++j) pmaxs[w][c * 8 + j] = (unsigned short)mx[j];
    }
  }

  // h store: straight u16x8 copy, dense 16B/lane
  if (write_h) {
    u16x8* hout = reinterpret_cast<u16x8*>(h) + (size_t)blk * 1024;
#pragma unroll
    for (int i = 0; i < 4; ++i) {
      const int s = i * 256 + t;
      const int tl = s >> 8, ks = (s >> 6) & 3, lp = s & 63;
      const int row = tl * 16 + (lp & 15);
      const int c0 = ks * 32 + ((lp >> 4) << 3);
      hout[tl * 256 + ks * 64 + lp] =
          *reinterpret_cast<const u16x8*>(&hs[row * 136 + c0]);
    }
  }
  __syncthreads();
  if (t < 128) {
    int v = pmaxs[0][t];
    v = max(v, (int)pmaxs[1][t]);
    v = max(v, (int)pmaxs[2][t]);
    v = max(v, (int)pmaxs[3][t]);
    pm[(size_t)blk * 128 + t] = __builtin_bit_cast(float, ((unsigned)v) << 16);
  }
}

// ---------------------------------------------------------------------------
// Layer 0: h = relu( relu(p@Wpos+bpos) @ W0 + b0 ), pm per block.
// ---------------------------------------------------------------------------
__global__ __launch_bounds__(256, 7) void k_layer0(
    const float* __restrict__ p, const float* __restrict__ Wpos,
    const float* __restrict__ bpos, const float* __restrict__ b0,
    const unsigned short* __restrict__ Wt0, unsigned short* __restrict__ h,
    float* __restrict__ pm) {
  __shared__ float wls[1024];                 // Wpos (3x256) + bpos
  __shared__ unsigned short hs[64 * 136];     // 17.4 KB bf16 tile
  __shared__ unsigned short pmaxs[4][128];
  const int t = threadIdx.x, blk = blockIdx.x;
  for (int i = t; i < 1024; i += 256) wls[i] = (i < 768) ? Wpos[i] : bpos[i - 768];

  const int w = t >> 6, lane = t & 63, g = lane >> 4;
  const int row = blk * 64 + w * 16 + (lane & 15);
  const float p0 = p[row * 3 + 0], p1 = p[row * 3 + 1], p2 = p[row * 3 + 2];

  float bias[8];
#pragma unroll
  for (int nt = 0; nt < 8; ++nt) bias[nt] = b0[nt * 16 + (lane & 15)];

  f32x4 acc[8];
#pragma unroll
  for (int nt = 0; nt < 8; ++nt) acc[nt] = f32x4{0.f, 0.f, 0.f, 0.f};
  __syncthreads();

#pragma unroll
  for (int ks = 0; ks < 8; ++ks) {
    FragU a;
    const int kb = ks * 32 + g * 8;
#pragma unroll
    for (int half = 0; half < 2; ++half) {
      const int kq = kb + half * 4;
      const float4 w0 = *reinterpret_cast<const float4*>(&wls[kq]);
      const float4 w1 = *reinterpret_cast<const float4*>(&wls[256 + kq]);
      const float4 w2 = *reinterpret_cast<const float4*>(&wls[512 + kq]);
      const float4 bb = *reinterpret_cast<const float4*>(&wls[768 + kq]);
      a.us[half * 4 + 0] = f2bf(fmaxf(bb.x + p0 * w0.x + p1 * w1.x + p2 * w2.x, 0.f));
      a.us[half * 4 + 1] = f2bf(fmaxf(bb.y + p0 * w0.y + p1 * w1.y + p2 * w2.y, 0.f));
      a.us[half * 4 + 2] = f2bf(fmaxf(bb.z + p0 * w0.z + p1 * w1.z + p2 * w2.z, 0.f));
      a.us[half * 4 + 3] = f2bf(fmaxf(bb.w + p0 * w0.w + p1 * w1.w + p2 * w2.w, 0.f));
    }
    const bf16x8* Bf = reinterpret_cast<const bf16x8*>(Wt0) + (ks * 512 + lane);
#pragma unroll
    for (int nt = 0; nt < 8; ++nt) acc[nt] = mfma16(a.v, Bf[nt * 64], acc[nt]);
  }
  epilogue16(hs, pmaxs, acc, bias, t, blk, h, pm, true);
}

// ---------------------------------------------------------------------------
// Pooled layer: h = relu( h @ Wa + c[b] )  (h already relu'd bf16, frag order)
// ---------------------------------------------------------------------------
__global__ __launch_bounds__(256, 8) void k_layer(
    const unsigned short* __restrict__ Wta, const float* __restrict__ cvec,
    unsigned short* __restrict__ h, float* __restrict__ pm, int write_h) {
  __shared__ unsigned short hs[64 * 136];
  __shared__ unsigned short pmaxs[4][128];
  const int t = threadIdx.x, blk = blockIdx.x;
  const int w = t >> 6, lane = t & 63;
  const int b = blk >> 7;

  float bias[8];
#pragma unroll
  for (int nt = 0; nt < 8; ++nt) bias[nt] = cvec[b * 128 + nt * 16 + (lane & 15)];

  f32x4 acc[8];
#pragma unroll
  for (int nt = 0; nt < 8; ++nt) acc[nt] = f32x4{0.f, 0.f, 0.f, 0.f};

  const u16x8* hA = reinterpret_cast<const u16x8*>(h) + ((size_t)(blk * 4 + w)) * 256;
#pragma unroll
  for (int ks = 0; ks < 4; ++ks) {
    FragU a;
    a.u = hA[ks * 64 + lane];                 // already relu'd
    const bf16x8* Bf = reinterpret_cast<const bf16x8*>(Wta) + (ks * 512 + lane);
#pragma unroll
    for (int nt = 0; nt < 8; ++nt) acc[nt] = mfma16(a.v, Bf[nt * 64], acc[nt]);
  }
  epilogue16(hs, pmaxs, acc, bias, t, blk, h, pm, write_h != 0);
}

// ---------------------------------------------------------------------------
// Combine: m[b] = max over 128 partials; c[b][n] = relu(m)@Wn[128:256] + bn
// ---------------------------------------------------------------------------
__global__ __launch_bounds__(256) void k_combine(
    const float* __restrict__ pm, const float* __restrict__ Wn,
    const float* __restrict__ bn, float* __restrict__ cout) {
  const int b = blockIdx.x, t = threadIdx.x;
  const int f = t & 127, half = t >> 7;
  __shared__ float part[2][128];
  __shared__ float rm[128];
  float m = 0.f;
  for (int i = half * 64; i < half * 64 + 64; ++i)
    m = fmaxf(m, pm[(size_t)(b * 128 + i) * 128 + f]);
  part[half][f] = m;
  __syncthreads();
  if (t < 128) rm[f] = fmaxf(part[0][f], part[1][f]);
  __syncthreads();
  float s = 0.f;
  for (int q = half * 64; q < half * 64 + 64; ++q)
    s += rm[q] * Wn[(128 + q) * 128 + f];
  part[half][f] = s;
  __syncthreads();
  if (t < 128) cout[b * 128 + f] = part[0][f] + part[1][f] + bn[f];
}

// ---------------------------------------------------------------------------
// Final: g = max over partials; 5-layer head MLP (fp32); out fp32 [32,9]
// ---------------------------------------------------------------------------
__global__ __launch_bounds__(256) void k_final(
    const float* __restrict__ pm3,
    const float* __restrict__ Wc,  const float* __restrict__ bc,
    const float* __restrict__ Wm0, const float* __restrict__ bm0,
    const float* __restrict__ Wm1, const float* __restrict__ bm1,
    const float* __restrict__ Wm2, const float* __restrict__ bm2,
    const float* __restrict__ Wp,  const float* __restrict__ bp,
    float* __restrict__ out) {
  const int b = blockIdx.x, t = threadIdx.x;
  const int f = t & 127, half = t >> 7;
  __shared__ float part[2][128];
  __shared__ float x[128];
  float m = 0.f;
  for (int i = half * 64; i < half * 64 + 64; ++i)
    m = fmaxf(m, pm3[(size_t)(b * 128 + i) * 128 + f]);
  part[half][f] = m;
  __syncthreads();
  if (t < 128) x[f] = fmaxf(part[0][f], part[1][f]);
  __syncthreads();

  const float* Ws[4] = {Wc, Wm0, Wm1, Wm2};
  const float* bs[4] = {bc, bm0, bm1, bm2};
#pragma unroll
  for (int L = 0; L < 4; ++L) {
    float s = 0.f;
    for (int q = half * 64; q < half * 64 + 64; ++q)
      s += x[q] * Ws[L][q * 128 + f];
    part[half][f] = s;
    __syncthreads();
    if (t < 128) x[f] = fmaxf(part[0][f] + part[1][f] + bs[L][f], 0.f);
    __syncthreads();
  }
  if (t < 9) {
    float s = bp[t];
    for (int q = 0; q < 128; ++q) s += x[q] * Wp[q * 9 + t];
    out[b * 9 + t] = s;
  }
}

// ---------------------------------------------------------------------------
extern "C" void kernel_launch(void* const* d_in, const int* in_sizes, int n_in,
                              void* d_out, int out_size, void* d_ws, size_t ws_size,
                              hipStream_t stream) {
  const float *p = nullptr, *Wpos = nullptr, *bpos = nullptr;
  const float *Wp = nullptr, *bp = nullptr;
  const float *W256[4] = {}; int nW256 = 0;
  const float *W128[4] = {}; int nW128 = 0;
  const float *B128[8] = {}; int nB128 = 0;
  for (int i = 0; i < n_in; ++i) {
    const float* q = (const float*)d_in[i];
    switch (in_sizes[i]) {
      case 786432: p = q; break;
      case 768:    Wpos = q; break;
      case 256:    bpos = q; break;
      case 1152:   Wp = q; break;
      case 9:      bp = q; break;
      case 32768:  if (nW256 < 4) W256[nW256++] = q; break;
      case 16384:  if (nW128 < 4) W128[nW128++] = q; break;
      case 128:    if (nB128 < 8) B128[nB128++] = q; break;
      default: break;
    }
  }
  const float *W0 = W256[0], *W1 = W256[1], *W2 = W256[2], *W3 = W256[3];
  const float *Wc = W128[0], *Wm0 = W128[1], *Wm1 = W128[2], *Wm2 = W128[3];
  const float *b0 = B128[0], *b1 = B128[1], *b2 = B128[2], *b3 = B128[3];
  const float *bc = B128[4], *bm0 = B128[5], *bm1 = B128[6], *bm2 = B128[7];
  float* out = (float*)d_out;

  // ws layout (~66.2 MB)
  char* ws = (char*)d_ws;
  float* pm = (float*)ws;                                        // 2 MiB
  float* cv = (float*)(ws + 2097152);                            // 16 KiB
  unsigned short* Wt = (unsigned short*)(ws + 2097152 + 16384);  // 160 KiB
  unsigned short* Wt0 = Wt;
  unsigned short* Wt1 = Wt + 32768;
  unsigned short* Wt2 = Wt + 49152;
  unsigned short* Wt3 = Wt + 65536;
  unsigned short* h = Wt + 81920;                                // 64 MiB

  k_pack_all<<<40, 256, 0, stream>>>(W0, W1, W2, W3, Wt);
  k_layer0<<<4096, 256, 0, stream>>>(p, Wpos, bpos, b0, Wt0, h, pm);
  k_combine<<<32, 256, 0, stream>>>(pm, W1, b1, cv);
  k_layer<<<4096, 256, 0, stream>>>(Wt1, cv, h, pm, 1);
  k_combine<<<32, 256, 0, stream>>>(pm, W2, b2, cv);
  k_layer<<<4096, 256, 0, stream>>>(Wt2, cv, h, pm, 1);
  k_combine<<<32, 256, 0, stream>>>(pm, W3, b3, cv);
  k_layer<<<4096, 256, 0, stream>>>(Wt3, cv, h, pm, 0);
  k_final<<<32, 256, 0, stream>>>(pm, Wc, bc, Wm0, bm0, Wm1, bm1, Wm2, bm2, Wp, bp, out);
}

// Round 8
// 163.283 us; speedup vs baseline: 1.2879x; 1.2879x over previous
//
#include <hip/hip_runtime.h>

// FCPlanenet on MI355X (gfx950). fp32 inputs, fp32 output [32*9].
// Round 8: B-reuse tiling. Wave tile 16x128 -> 64x128 (4 m-frags), block=256
// rows, grid=1024. Per ks: 8 B-frags loaded to regs ONCE, reused by 4 A-frags
// (MFMA:B-load 4:1, aggregate B traffic /4 vs R7 — R7 was L1/L2-thrash-bound).
// pm computed from registers (relu(max)=max(relu)); LDS tile only for the
// h-format transpose; layer3 skips LDS/h entirely.
// h layout (frag order, verified R6/R7): 16-row tile tl -> 256 u16x8 slots,
//   slot[ks*64+lane] = rows tl*16+(lane&15), cols ks*32+(lane>>4)*8..+7.
// C/D map (probe-verified R3/R4): col=lane&15, row=(lane>>4)*4+r.

using bf16x8 = __attribute__((ext_vector_type(8))) __bf16;
using u16x8  = __attribute__((ext_vector_type(8))) unsigned short;
using f32x4  = __attribute__((ext_vector_type(4))) float;

__device__ __forceinline__ unsigned short f2bf(float x) {
  __bf16 b = (__bf16)x;
  return __builtin_bit_cast(unsigned short, b);
}

__device__ __forceinline__ f32x4 mfma16(bf16x8 a, bf16x8 b, f32x4 c) {
  return __builtin_amdgcn_mfma_f32_16x16x32_bf16(a, b, c, 0, 0, 0);
}

union FragU { unsigned short us[8]; u16x8 u; bf16x8 v; };

// ---------------------------------------------------------------------------
// Pack all four W (fp32 KxN, N=128) -> frag-ordered bf16 into one buffer.
// slot = (ks*8 + nt)*64 + lane ; holds W[ks*32+(lane>>4)*8+j][nt*16+(lane&15)]
// ---------------------------------------------------------------------------
__global__ __launch_bounds__(256) void k_pack_all(
    const float* __restrict__ W0, const float* __restrict__ W1,
    const float* __restrict__ W2, const float* __restrict__ W3,
    unsigned short* __restrict__ Wt) {
  const int blk = blockIdx.x, t = threadIdx.x;
  const float* src; int slot; unsigned short* dst;
  if (blk < 16)      { src = W0; slot = blk * 256 + t;        dst = Wt; }
  else if (blk < 24) { src = W1; slot = (blk - 16) * 256 + t; dst = Wt + 32768; }
  else if (blk < 32) { src = W2; slot = (blk - 24) * 256 + t; dst = Wt + 49152; }
  else               { src = W3; slot = (blk - 32) * 256 + t; dst = Wt + 65536; }
  const int ks = slot >> 9, rem = slot & 511;
  const int nt = rem >> 6, lane = rem & 63;
  const int n = nt * 16 + (lane & 15);
  const int kb = ks * 32 + ((lane >> 4) << 3);
  FragU fr;
#pragma unroll
  for (int j = 0; j < 8; ++j) fr.us[j] = f2bf(src[(kb + j) * 128 + n]);
  reinterpret_cast<u16x8*>(dst)[slot] = fr.u;
}

// ---------------------------------------------------------------------------
// Shared epilogue for 256-row blocks: pm from registers; optional h transpose
// through LDS (write_h).
// ---------------------------------------------------------------------------
__device__ __forceinline__ void epilogue256(
    unsigned short* hs, float (*pmaxs)[128], const f32x4 (&acc)[4][8],
    const float (&bias)[8], int t, int blk, unsigned short* __restrict__ h,
    float* __restrict__ pm, bool write_h) {
  const int w = t >> 6, lane = t & 63, g = lane >> 4, c = lane & 15;
  float colmax[8];
#pragma unroll
  for (int nt = 0; nt < 8; ++nt) colmax[nt] = 0.f;
#pragma unroll
  for (int mi = 0; mi < 4; ++mi) {
#pragma unroll
    for (int nt = 0; nt < 8; ++nt) {
#pragma unroll
      for (int r = 0; r < 4; ++r) {
        const float v = fmaxf(acc[mi][nt][r] + bias[nt], 0.f);
        colmax[nt] = fmaxf(colmax[nt], v);
        if (write_h)
          hs[(w * 64 + mi * 16 + g * 4 + r) * 136 + nt * 16 + c] = f2bf(v);
      }
    }
  }
#pragma unroll
  for (int nt = 0; nt < 8; ++nt) {
    colmax[nt] = fmaxf(colmax[nt], __shfl_xor(colmax[nt], 16, 64));
    colmax[nt] = fmaxf(colmax[nt], __shfl_xor(colmax[nt], 32, 64));
  }
  if (lane < 16) {
#pragma unroll
    for (int nt = 0; nt < 8; ++nt) pmaxs[w][nt * 16 + c] = colmax[nt];
  }
  __syncthreads();
  if (write_h) {
    u16x8* hout = reinterpret_cast<u16x8*>(h) + (size_t)blk * 4096;
#pragma unroll
    for (int i = 0; i < 16; ++i) {
      const int s = i * 256 + t;
      const int tl = s >> 8, ks = (s >> 6) & 3, lp = s & 63;
      const int row = tl * 16 + (lp & 15);
      const int c0 = ks * 32 + ((lp >> 4) << 3);
      hout[tl * 256 + ks * 64 + lp] =
          *reinterpret_cast<const u16x8*>(&hs[row * 136 + c0]);
    }
  }
  if (t < 128) {
    pm[(size_t)blk * 128 + t] = fmaxf(fmaxf(pmaxs[0][t], pmaxs[1][t]),
                                      fmaxf(pmaxs[2][t], pmaxs[3][t]));
  }
}

// ---------------------------------------------------------------------------
// Layer 0: h = relu( relu(p@Wpos+bpos) @ W0 + b0 ), 256 rows/block.
// ---------------------------------------------------------------------------
__global__ __launch_bounds__(256, 2) void k_layer0(
    const float* __restrict__ p, const float* __restrict__ Wpos,
    const float* __restrict__ bpos, const float* __restrict__ b0,
    const unsigned short* __restrict__ Wt0, unsigned short* __restrict__ h,
    float* __restrict__ pm) {
  __shared__ float wls[1024];                  // Wpos (3x256) + bpos
  __shared__ unsigned short hs[256 * 136];     // 69.6 KB bf16 transpose tile
  __shared__ float pmaxs[4][128];
  const int t = threadIdx.x, blk = blockIdx.x;
  for (int i = t; i < 1024; i += 256) wls[i] = (i < 768) ? Wpos[i] : bpos[i - 768];

  const int w = t >> 6, lane = t & 63, g = lane >> 4, c = lane & 15;
  float px[4], py[4], pz[4];
#pragma unroll
  for (int mi = 0; mi < 4; ++mi) {
    const int row = blk * 256 + (w * 4 + mi) * 16 + c;
    px[mi] = p[row * 3 + 0]; py[mi] = p[row * 3 + 1]; pz[mi] = p[row * 3 + 2];
  }
  float bias[8];
#pragma unroll
  for (int nt = 0; nt < 8; ++nt) bias[nt] = b0[nt * 16 + c];

  f32x4 acc[4][8];
#pragma unroll
  for (int mi = 0; mi < 4; ++mi)
#pragma unroll
    for (int nt = 0; nt < 8; ++nt) acc[mi][nt] = f32x4{0.f, 0.f, 0.f, 0.f};
  __syncthreads();

  const bf16x8* Bf = reinterpret_cast<const bf16x8*>(Wt0);
#pragma unroll
  for (int ks = 0; ks < 8; ++ks) {
    bf16x8 B[8];
#pragma unroll
    for (int nt = 0; nt < 8; ++nt) B[nt] = Bf[(ks * 8 + nt) * 64 + lane];
    FragU a[4];
    const int kb = ks * 32 + g * 8;
#pragma unroll
    for (int mi = 0; mi < 4; ++mi) {
#pragma unroll
      for (int half = 0; half < 2; ++half) {
        const int kq = kb + half * 4;
        const float4 w0 = *reinterpret_cast<const float4*>(&wls[kq]);
        const float4 w1 = *reinterpret_cast<const float4*>(&wls[256 + kq]);
        const float4 w2 = *reinterpret_cast<const float4*>(&wls[512 + kq]);
        const float4 bb = *reinterpret_cast<const float4*>(&wls[768 + kq]);
        a[mi].us[half * 4 + 0] = f2bf(fmaxf(bb.x + px[mi] * w0.x + py[mi] * w1.x + pz[mi] * w2.x, 0.f));
        a[mi].us[half * 4 + 1] = f2bf(fmaxf(bb.y + px[mi] * w0.y + py[mi] * w1.y + pz[mi] * w2.y, 0.f));
        a[mi].us[half * 4 + 2] = f2bf(fmaxf(bb.z + px[mi] * w0.z + py[mi] * w1.z + pz[mi] * w2.z, 0.f));
        a[mi].us[half * 4 + 3] = f2bf(fmaxf(bb.w + px[mi] * w0.w + py[mi] * w1.w + pz[mi] * w2.w, 0.f));
      }
    }
#pragma unroll
    for (int mi = 0; mi < 4; ++mi)
#pragma unroll
      for (int nt = 0; nt < 8; ++nt)
        acc[mi][nt] = mfma16(a[mi].v, B[nt], acc[mi][nt]);
  }
  epilogue256(hs, pmaxs, acc, bias, t, blk, h, pm, true);
}

// ---------------------------------------------------------------------------
// Pooled layer: h = relu( h @ Wa + c[b] ), 256 rows/block, in-place.
// ---------------------------------------------------------------------------
__global__ __launch_bounds__(256, 2) void k_layer(
    const unsigned short* __restrict__ Wta, const float* __restrict__ cvec,
    unsigned short* __restrict__ h, float* __restrict__ pm, int write_h) {
  __shared__ unsigned short hs[256 * 136];
  __shared__ float pmaxs[4][128];
  const int t = threadIdx.x, blk = blockIdx.x;
  const int w = t >> 6, lane = t & 63, c = lane & 15;
  const int b = blk >> 5;   // 32 blocks (of 256 rows) per batch of 8192

  float bias[8];
#pragma unroll
  for (int nt = 0; nt < 8; ++nt) bias[nt] = cvec[b * 128 + nt * 16 + c];

  f32x4 acc[4][8];
#pragma unroll
  for (int mi = 0; mi < 4; ++mi)
#pragma unroll
    for (int nt = 0; nt < 8; ++nt) acc[mi][nt] = f32x4{0.f, 0.f, 0.f, 0.f};

  const u16x8* hbase = reinterpret_cast<const u16x8*>(h) + (size_t)blk * 4096;
  const bf16x8* Bf = reinterpret_cast<const bf16x8*>(Wta);
#pragma unroll
  for (int ks = 0; ks < 4; ++ks) {
    bf16x8 B[8];
#pragma unroll
    for (int nt = 0; nt < 8; ++nt) B[nt] = Bf[(ks * 8 + nt) * 64 + lane];
    FragU a[4];
#pragma unroll
    for (int mi = 0; mi < 4; ++mi) a[mi].u = hbase[(w * 4 + mi) * 256 + ks * 64 + lane];
#pragma unroll
    for (int mi = 0; mi < 4; ++mi)
#pragma unroll
      for (int nt = 0; nt < 8; ++nt)
        acc[mi][nt] = mfma16(a[mi].v, B[nt], acc[mi][nt]);
  }
  epilogue256(hs, pmaxs, acc, bias, t, blk, h, pm, write_h != 0);
}

// ---------------------------------------------------------------------------
// Combine: m[b] = max over 32 partials; c[b][n] = relu(m)@Wn[128:256] + bn
// ---------------------------------------------------------------------------
__global__ __launch_bounds__(256) void k_combine(
    const float* __restrict__ pm, const float* __restrict__ Wn,
    const float* __restrict__ bn, float* __restrict__ cout) {
  const int b = blockIdx.x, t = threadIdx.x;
  const int f = t & 127, half = t >> 7;
  __shared__ float part[2][128];
  __shared__ float rm[128];
  float m = 0.f;
  for (int i = half * 16; i < half * 16 + 16; ++i)
    m = fmaxf(m, pm[(size_t)(b * 32 + i) * 128 + f]);
  part[half][f] = m;
  __syncthreads();
  if (t < 128) rm[f] = fmaxf(part[0][f], part[1][f]);
  __syncthreads();
  float s = 0.f;
  for (int q = half * 64; q < half * 64 + 64; ++q)
    s += rm[q] * Wn[(128 + q) * 128 + f];
  part[half][f] = s;
  __syncthreads();
  if (t < 128) cout[b * 128 + f] = part[0][f] + part[1][f] + bn[f];
}

// ---------------------------------------------------------------------------
// Final: g = max over 32 partials; 5-layer head MLP (fp32); out fp32 [32,9]
// ---------------------------------------------------------------------------
__global__ __launch_bounds__(256) void k_final(
    const float* __restrict__ pm3,
    const float* __restrict__ Wc,  const float* __restrict__ bc,
    const float* __restrict__ Wm0, const float* __restrict__ bm0,
    const float* __restrict__ Wm1, const float* __restrict__ bm1,
    const float* __restrict__ Wm2, const float* __restrict__ bm2,
    const float* __restrict__ Wp,  const float* __restrict__ bp,
    float* __restrict__ out) {
  const int b = blockIdx.x, t = threadIdx.x;
  const int f = t & 127, half = t >> 7;
  __shared__ float part[2][128];
  __shared__ float x[128];
  float m = 0.f;
  for (int i = half * 16; i < half * 16 + 16; ++i)
    m = fmaxf(m, pm3[(size_t)(b * 32 + i) * 128 + f]);
  part[half][f] = m;
  __syncthreads();
  if (t < 128) x[f] = fmaxf(part[0][f], part[1][f]);
  __syncthreads();

  const float* Ws[4] = {Wc, Wm0, Wm1, Wm2};
  const float* bs[4] = {bc, bm0, bm1, bm2};
#pragma unroll
  for (int L = 0; L < 4; ++L) {
    float s = 0.f;
    for (int q = half * 64; q < half * 64 + 64; ++q)
      s += x[q] * Ws[L][q * 128 + f];
    part[half][f] = s;
    __syncthreads();
    if (t < 128) x[f] = fmaxf(part[0][f] + part[1][f] + bs[L][f], 0.f);
    __syncthreads();
  }
  if (t < 9) {
    float s = bp[t];
    for (int q = 0; q < 128; ++q) s += x[q] * Wp[q * 9 + t];
    out[b * 9 + t] = s;
  }
}

// ---------------------------------------------------------------------------
extern "C" void kernel_launch(void* const* d_in, const int* in_sizes, int n_in,
                              void* d_out, int out_size, void* d_ws, size_t ws_size,
                              hipStream_t stream) {
  const float *p = nullptr, *Wpos = nullptr, *bpos = nullptr;
  const float *Wp = nullptr, *bp = nullptr;
  const float *W256[4] = {}; int nW256 = 0;
  const float *W128[4] = {}; int nW128 = 0;
  const float *B128[8] = {}; int nB128 = 0;
  for (int i = 0; i < n_in; ++i) {
    const float* q = (const float*)d_in[i];
    switch (in_sizes[i]) {
      case 786432: p = q; break;
      case 768:    Wpos = q; break;
      case 256:    bpos = q; break;
      case 1152:   Wp = q; break;
      case 9:      bp = q; break;
      case 32768:  if (nW256 < 4) W256[nW256++] = q; break;
      case 16384:  if (nW128 < 4) W128[nW128++] = q; break;
      case 128:    if (nB128 < 8) B128[nB128++] = q; break;
      default: break;
    }
  }
  const float *W0 = W256[0], *W1 = W256[1], *W2 = W256[2], *W3 = W256[3];
  const float *Wc = W128[0], *Wm0 = W128[1], *Wm1 = W128[2], *Wm2 = W128[3];
  const float *b0 = B128[0], *b1 = B128[1], *b2 = B128[2], *b3 = B128[3];
  const float *bc = B128[4], *bm0 = B128[5], *bm1 = B128[6], *bm2 = B128[7];
  float* out = (float*)d_out;

  // ws layout (~65 MB)
  char* ws = (char*)d_ws;
  float* pm = (float*)ws;                                        // 512 KiB
  float* cv = (float*)(ws + 524288);                             // 16 KiB
  unsigned short* Wt = (unsigned short*)(ws + 524288 + 16384);   // 160 KiB
  unsigned short* Wt0 = Wt;
  unsigned short* Wt1 = Wt + 32768;
  unsigned short* Wt2 = Wt + 49152;
  unsigned short* Wt3 = Wt + 65536;
  unsigned short* h = Wt + 81920;                                // 64 MiB

  k_pack_all<<<40, 256, 0, stream>>>(W0, W1, W2, W3, Wt);
  k_layer0<<<1024, 256, 0, stream>>>(p, Wpos, bpos, b0, Wt0, h, pm);
  k_combine<<<32, 256, 0, stream>>>(pm, W1, b1, cv);
  k_layer<<<1024, 256, 0, stream>>>(Wt1, cv, h, pm, 1);
  k_combine<<<32, 256, 0, stream>>>(pm, W2, b2, cv);
  k_layer<<<1024, 256, 0, stream>>>(Wt2, cv, h, pm, 1);
  k_combine<<<32, 256, 0, stream>>>(pm, W3, b3, cv);
  k_layer<<<1024, 256, 0, stream>>>(Wt3, cv, h, pm, 0);
  k_final<<<32, 256, 0, stream>>>(pm, Wc, bc, Wm0, bm0, Wm1, bm1, Wm2, bm2, Wp, bp, out);
}

// Round 9
// 160.280 us; speedup vs baseline: 1.3120x; 1.0187x over previous
//
#include <hip/hip_runtime.h>

// FCPlanenet on MI355X (gfx950). fp32 inputs, fp32 output [32*9].
// Round 9: spill fix. Wave tile 32x128 (acc[2][8]=64 VGPR), 512-thread
// blocks (8 waves, 256 rows), B loaded per-(ks,nt) reused across 2 m-frags.
// Wave-local LDS transpose (4.35KB/wave, no block barrier; same-wave DS ops
// are ordered). pm from registers + shfl_xor. Layer3 skips LDS/h.
// h layout (frag order, verified R6-R8): block blk owns 4096 u16x8 slots;
//   slot[tl*256 + ks*64 + lane] = row blk*256+tl*16+(lane&15),
//   cols ks*32+(lane>>4)*8..+7.
// C/D map (probe-verified R3/R4): col=lane&15, row=(lane>>4)*4+r.

using bf16x8 = __attribute__((ext_vector_type(8))) __bf16;
using u16x8  = __attribute__((ext_vector_type(8))) unsigned short;
using f32x4  = __attribute__((ext_vector_type(4))) float;

__device__ __forceinline__ unsigned short f2bf(float x) {
  __bf16 b = (__bf16)x;
  return __builtin_bit_cast(unsigned short, b);
}

__device__ __forceinline__ f32x4 mfma16(bf16x8 a, bf16x8 b, f32x4 c) {
  return __builtin_amdgcn_mfma_f32_16x16x32_bf16(a, b, c, 0, 0, 0);
}

union FragU { unsigned short us[8]; u16x8 u; bf16x8 v; };

// ---------------------------------------------------------------------------
// Pack all four W (fp32 KxN, N=128) -> frag-ordered bf16 into one buffer.
// slot = (ks*8 + nt)*64 + lane ; holds W[ks*32+(lane>>4)*8+j][nt*16+(lane&15)]
// ---------------------------------------------------------------------------
__global__ __launch_bounds__(256) void k_pack_all(
    const float* __restrict__ W0, const float* __restrict__ W1,
    const float* __restrict__ W2, const float* __restrict__ W3,
    unsigned short* __restrict__ Wt) {
  const int blk = blockIdx.x, t = threadIdx.x;
  const float* src; int slot; unsigned short* dst;
  if (blk < 16)      { src = W0; slot = blk * 256 + t;        dst = Wt; }
  else if (blk < 24) { src = W1; slot = (blk - 16) * 256 + t; dst = Wt + 32768; }
  else if (blk < 32) { src = W2; slot = (blk - 24) * 256 + t; dst = Wt + 49152; }
  else               { src = W3; slot = (blk - 32) * 256 + t; dst = Wt + 65536; }
  const int ks = slot >> 9, rem = slot & 511;
  const int nt = rem >> 6, lane = rem & 63;
  const int n = nt * 16 + (lane & 15);
  const int kb = ks * 32 + ((lane >> 4) << 3);
  FragU fr;
#pragma unroll
  for (int j = 0; j < 8; ++j) fr.us[j] = f2bf(src[(kb + j) * 128 + n]);
  reinterpret_cast<u16x8*>(dst)[slot] = fr.u;
}

// ---------------------------------------------------------------------------
// Epilogue for 512-thread blocks: pm from regs; wave-local LDS transpose for
// frag-order h write. hsw = this wave's 2176-u16 buffer (16 rows x 136).
// ---------------------------------------------------------------------------
__device__ __forceinline__ void epilogue512(
    unsigned short* hsw, float (*pmaxs)[128], const f32x4 (&acc)[2][8],
    const float (&bias)[8], int t, int blk, unsigned short* __restrict__ h,
    float* __restrict__ pm, bool write_h) {
  const int w = t >> 6, lane = t & 63, g = lane >> 4, c = lane & 15;
  float colmax[8];
#pragma unroll
  for (int nt = 0; nt < 8; ++nt) colmax[nt] = 0.f;

  if (write_h) {
    u16x8* hout = reinterpret_cast<u16x8*>(h) + (size_t)blk * 4096;
#pragma unroll
    for (int mi = 0; mi < 2; ++mi) {
#pragma unroll
      for (int nt = 0; nt < 8; ++nt) {
#pragma unroll
        for (int r = 0; r < 4; ++r) {
          const float v = fmaxf(acc[mi][nt][r] + bias[nt], 0.f);
          colmax[nt] = fmaxf(colmax[nt], v);
          hsw[(g * 4 + r) * 136 + nt * 16 + c] = f2bf(v);
        }
      }
      // wave-local read-back (same-wave DS ordering; compiler emits lgkmcnt)
#pragma unroll
      for (int s = 0; s < 4; ++s) {
        const u16x8 val =
            *reinterpret_cast<const u16x8*>(&hsw[(lane & 15) * 136 + s * 32 + 8 * g]);
        hout[(w * 2 + mi) * 256 + s * 64 + lane] = val;
      }
    }
  } else {
#pragma unroll
    for (int mi = 0; mi < 2; ++mi)
#pragma unroll
      for (int nt = 0; nt < 8; ++nt)
#pragma unroll
        for (int r = 0; r < 4; ++r)
          colmax[nt] = fmaxf(colmax[nt], acc[mi][nt][r] + bias[nt]);
    // colmax init 0 == relu
  }

#pragma unroll
  for (int nt = 0; nt < 8; ++nt) {
    colmax[nt] = fmaxf(colmax[nt], __shfl_xor(colmax[nt], 16, 64));
    colmax[nt] = fmaxf(colmax[nt], __shfl_xor(colmax[nt], 32, 64));
  }
  if (lane < 16) {
#pragma unroll
    for (int nt = 0; nt < 8; ++nt) pmaxs[w][nt * 16 + c] = colmax[nt];
  }
  __syncthreads();
  if (t < 128) {
    float m = pmaxs[0][t];
#pragma unroll
    for (int i = 1; i < 8; ++i) m = fmaxf(m, pmaxs[i][t]);
    pm[(size_t)blk * 128 + t] = m;
  }
}

// ---------------------------------------------------------------------------
// Layer 0: h = relu( relu(p@Wpos+bpos) @ W0 + b0 ), 256 rows/block, 8 waves.
// ---------------------------------------------------------------------------
__global__ __launch_bounds__(512, 4) void k_layer0(
    const float* __restrict__ p, const float* __restrict__ Wpos,
    const float* __restrict__ bpos, const float* __restrict__ b0,
    const unsigned short* __restrict__ Wt0, unsigned short* __restrict__ h,
    float* __restrict__ pm) {
  __shared__ float wls[1024];                 // Wpos (3x256) + bpos
  __shared__ unsigned short HS[8 * 2176];     // 8 wave-local transpose bufs
  __shared__ float pmaxs[8][128];
  const int t = threadIdx.x, blk = blockIdx.x;
  for (int i = t; i < 1024; i += 512) wls[i] = (i < 768) ? Wpos[i] : bpos[i - 768];

  const int w = t >> 6, lane = t & 63, g = lane >> 4, c = lane & 15;
  float px[2], py[2], pz[2];
#pragma unroll
  for (int mi = 0; mi < 2; ++mi) {
    const int row = blk * 256 + (w * 2 + mi) * 16 + c;
    px[mi] = p[row * 3 + 0]; py[mi] = p[row * 3 + 1]; pz[mi] = p[row * 3 + 2];
  }
  float bias[8];
#pragma unroll
  for (int nt = 0; nt < 8; ++nt) bias[nt] = b0[nt * 16 + c];

  f32x4 acc[2][8];
#pragma unroll
  for (int mi = 0; mi < 2; ++mi)
#pragma unroll
    for (int nt = 0; nt < 8; ++nt) acc[mi][nt] = f32x4{0.f, 0.f, 0.f, 0.f};
  __syncthreads();

  const bf16x8* Bf = reinterpret_cast<const bf16x8*>(Wt0);
#pragma unroll
  for (int ks = 0; ks < 8; ++ks) {
    FragU a[2];
    const int kb = ks * 32 + g * 8;
#pragma unroll
    for (int mi = 0; mi < 2; ++mi) {
#pragma unroll
      for (int half = 0; half < 2; ++half) {
        const int kq = kb + half * 4;
        const float4 w0 = *reinterpret_cast<const float4*>(&wls[kq]);
        const float4 w1 = *reinterpret_cast<const float4*>(&wls[256 + kq]);
        const float4 w2 = *reinterpret_cast<const float4*>(&wls[512 + kq]);
        const float4 bb = *reinterpret_cast<const float4*>(&wls[768 + kq]);
        a[mi].us[half * 4 + 0] = f2bf(fmaxf(bb.x + px[mi] * w0.x + py[mi] * w1.x + pz[mi] * w2.x, 0.f));
        a[mi].us[half * 4 + 1] = f2bf(fmaxf(bb.y + px[mi] * w0.y + py[mi] * w1.y + pz[mi] * w2.y, 0.f));
        a[mi].us[half * 4 + 2] = f2bf(fmaxf(bb.z + px[mi] * w0.z + py[mi] * w1.z + pz[mi] * w2.z, 0.f));
        a[mi].us[half * 4 + 3] = f2bf(fmaxf(bb.w + px[mi] * w0.w + py[mi] * w1.w + pz[mi] * w2.w, 0.f));
      }
    }
#pragma unroll
    for (int nt = 0; nt < 8; ++nt) {
      const bf16x8 B = Bf[(ks * 8 + nt) * 64 + lane];
      acc[0][nt] = mfma16(a[0].v, B, acc[0][nt]);
      acc[1][nt] = mfma16(a[1].v, B, acc[1][nt]);
    }
  }
  epilogue512(&HS[w * 2176], pmaxs, acc, bias, t, blk, h, pm, true);
}

// ---------------------------------------------------------------------------
// Pooled layer: h = relu( h @ Wa + c[b] ), 256 rows/block, 8 waves, in-place.
// ---------------------------------------------------------------------------
__global__ __launch_bounds__(512, 4) void k_layer(
    const unsigned short* __restrict__ Wta, const float* __restrict__ cvec,
    unsigned short* __restrict__ h, float* __restrict__ pm, int write_h) {
  __shared__ unsigned short HS[8 * 2176];
  __shared__ float pmaxs[8][128];
  const int t = threadIdx.x, blk = blockIdx.x;
  const int w = t >> 6, lane = t & 63, c = lane & 15;
  const int b = blk >> 5;   // 32 blocks (of 256 rows) per batch of 8192

  float bias[8];
#pragma unroll
  for (int nt = 0; nt < 8; ++nt) bias[nt] = cvec[b * 128 + nt * 16 + c];

  f32x4 acc[2][8];
#pragma unroll
  for (int mi = 0; mi < 2; ++mi)
#pragma unroll
    for (int nt = 0; nt < 8; ++nt) acc[mi][nt] = f32x4{0.f, 0.f, 0.f, 0.f};

  const u16x8* hbase = reinterpret_cast<const u16x8*>(h) + (size_t)blk * 4096;
  const bf16x8* Bf = reinterpret_cast<const bf16x8*>(Wta);
#pragma unroll
  for (int ks = 0; ks < 4; ++ks) {
    FragU a0, a1;
    a0.u = hbase[(w * 2 + 0) * 256 + ks * 64 + lane];
    a1.u = hbase[(w * 2 + 1) * 256 + ks * 64 + lane];
#pragma unroll
    for (int nt = 0; nt < 8; ++nt) {
      const bf16x8 B = Bf[(ks * 8 + nt) * 64 + lane];
      acc[0][nt] = mfma16(a0.v, B, acc[0][nt]);
      acc[1][nt] = mfma16(a1.v, B, acc[1][nt]);
    }
  }
  epilogue512(&HS[w * 2176], pmaxs, acc, bias, t, blk, h, pm, write_h != 0);
}

// ---------------------------------------------------------------------------
// Combine: m[b] = max over 32 partials; c[b][n] = relu(m)@Wn[128:256] + bn
// ---------------------------------------------------------------------------
__global__ __launch_bounds__(256) void k_combine(
    const float* __restrict__ pm, const float* __restrict__ Wn,
    const float* __restrict__ bn, float* __restrict__ cout) {
  const int b = blockIdx.x, t = threadIdx.x;
  const int f = t & 127, half = t >> 7;
  __shared__ float part[2][128];
  __shared__ float rm[128];
  float m = 0.f;
  for (int i = half * 16; i < half * 16 + 16; ++i)
    m = fmaxf(m, pm[(size_t)(b * 32 + i) * 128 + f]);
  part[half][f] = m;
  __syncthreads();
  if (t < 128) rm[f] = fmaxf(part[0][f], part[1][f]);
  __syncthreads();
  float s = 0.f;
  for (int q = half * 64; q < half * 64 + 64; ++q)
    s += rm[q] * Wn[(128 + q) * 128 + f];
  part[half][f] = s;
  __syncthreads();
  if (t < 128) cout[b * 128 + f] = part[0][f] + part[1][f] + bn[f];
}

// ---------------------------------------------------------------------------
// Final: g = max over 32 partials; 5-layer head MLP (fp32); out fp32 [32,9]
// ---------------------------------------------------------------------------
__global__ __launch_bounds__(256) void k_final(
    const float* __restrict__ pm3,
    const float* __restrict__ Wc,  const float* __restrict__ bc,
    const float* __restrict__ Wm0, const float* __restrict__ bm0,
    const float* __restrict__ Wm1, const float* __restrict__ bm1,
    const float* __restrict__ Wm2, const float* __restrict__ bm2,
    const float* __restrict__ Wp,  const float* __restrict__ bp,
    float* __restrict__ out) {
  const int b = blockIdx.x, t = threadIdx.x;
  const int f = t & 127, half = t >> 7;
  __shared__ float part[2][128];
  __shared__ float x[128];
  float m = 0.f;
  for (int i = half * 16; i < half * 16 + 16; ++i)
    m = fmaxf(m, pm3[(size_t)(b * 32 + i) * 128 + f]);
  part[half][f] = m;
  __syncthreads();
  if (t < 128) x[f] = fmaxf(part[0][f], part[1][f]);
  __syncthreads();

  const float* Ws[4] = {Wc, Wm0, Wm1, Wm2};
  const float* bs[4] = {bc, bm0, bm1, bm2};
#pragma unroll
  for (int L = 0; L < 4; ++L) {
    float s = 0.f;
    for (int q = half * 64; q < half * 64 + 64; ++q)
      s += x[q] * Ws[L][q * 128 + f];
    part[half][f] = s;
    __syncthreads();
    if (t < 128) x[f] = fmaxf(part[0][f] + part[1][f] + bs[L][f], 0.f);
    __syncthreads();
  }
  if (t < 9) {
    float s = bp[t];
    for (int q = 0; q < 128; ++q) s += x[q] * Wp[q * 9 + t];
    out[b * 9 + t] = s;
  }
}

// ---------------------------------------------------------------------------
extern "C" void kernel_launch(void* const* d_in, const int* in_sizes, int n_in,
                              void* d_out, int out_size, void* d_ws, size_t ws_size,
                              hipStream_t stream) {
  const float *p = nullptr, *Wpos = nullptr, *bpos = nullptr;
  const float *Wp = nullptr, *bp = nullptr;
  const float *W256[4] = {}; int nW256 = 0;
  const float *W128[4] = {}; int nW128 = 0;
  const float *B128[8] = {}; int nB128 = 0;
  for (int i = 0; i < n_in; ++i) {
    const float* q = (const float*)d_in[i];
    switch (in_sizes[i]) {
      case 786432: p = q; break;
      case 768:    Wpos = q; break;
      case 256:    bpos = q; break;
      case 1152:   Wp = q; break;
      case 9:      bp = q; break;
      case 32768:  if (nW256 < 4) W256[nW256++] = q; break;
      case 16384:  if (nW128 < 4) W128[nW128++] = q; break;
      case 128:    if (nB128 < 8) B128[nB128++] = q; break;
      default: break;
    }
  }
  const float *W0 = W256[0], *W1 = W256[1], *W2 = W256[2], *W3 = W256[3];
  const float *Wc = W128[0], *Wm0 = W128[1], *Wm1 = W128[2], *Wm2 = W128[3];
  const float *b0 = B128[0], *b1 = B128[1], *b2 = B128[2], *b3 = B128[3];
  const float *bc = B128[4], *bm0 = B128[5], *bm1 = B128[6], *bm2 = B128[7];
  float* out = (float*)d_out;

  // ws layout (~65 MB)
  char* ws = (char*)d_ws;
  float* pm = (float*)ws;                                        // 512 KiB
  float* cv = (float*)(ws + 524288);                             // 16 KiB
  unsigned short* Wt = (unsigned short*)(ws + 524288 + 16384);   // 160 KiB
  unsigned short* Wt0 = Wt;
  unsigned short* Wt1 = Wt + 32768;
  unsigned short* Wt2 = Wt + 49152;
  unsigned short* Wt3 = Wt + 65536;
  unsigned short* h = Wt + 81920;                                // 64 MiB

  k_pack_all<<<40, 256, 0, stream>>>(W0, W1, W2, W3, Wt);
  k_layer0<<<1024, 512, 0, stream>>>(p, Wpos, bpos, b0, Wt0, h, pm);
  k_combine<<<32, 256, 0, stream>>>(pm, W1, b1, cv);
  k_layer<<<1024, 512, 0, stream>>>(Wt1, cv, h, pm, 1);
  k_combine<<<32, 256, 0, stream>>>(pm, W2, b2, cv);
  k_layer<<<1024, 512, 0, stream>>>(Wt2, cv, h, pm, 1);
  k_combine<<<32, 256, 0, stream>>>(pm, W3, b3, cv);
  k_layer<<<1024, 512, 0, stream>>>(Wt3, cv, h, pm, 0);
  k_final<<<32, 256, 0, stream>>>(pm, Wc, bc, Wm0, bm0, Wm1, bm1, Wm2, bm2, Wp, bp, out);
}